// Round 7
// baseline (486.181 us; speedup 1.0000x reference)
//
#include <hip/hip_runtime.h>
#include <hip/hip_cooperative_groups.h>
#include <math.h>

namespace cg = cooperative_groups;

#define N 512
#define CS 514
#define NP 48
#define S8 0.70710678118654752440f

__device__ __forceinline__ float2 cadd(float2 a, float2 b){ return make_float2(a.x+b.x, a.y+b.y); }
__device__ __forceinline__ float2 csub(float2 a, float2 b){ return make_float2(a.x-b.x, a.y-b.y); }
__device__ __forceinline__ float2 cmul(float2 a, float2 b){
    return make_float2(fmaf(a.x,b.x,-(a.y*b.y)), fmaf(a.x,b.y, a.y*b.x));
}
template<int INV> __device__ __forceinline__ float2 rot90(float2 a){
    return INV ? make_float2(-a.y, a.x) : make_float2(a.y, -a.x);          // *(∓i)
}
template<int INV> __device__ __forceinline__ float2 rotW1(float2 a){       // *W8^{±1}
    return INV ? make_float2(S8*(a.x-a.y), S8*(a.x+a.y))
               : make_float2(S8*(a.x+a.y), S8*(a.y-a.x));
}
template<int INV> __device__ __forceinline__ float2 rotW3(float2 a){       // *W8^{±3}
    return INV ? make_float2(-S8*(a.x+a.y), S8*(a.x-a.y))
               : make_float2(S8*(a.y-a.x), -S8*(a.x+a.y));
}

template<int INV>
__device__ __forceinline__ void fft8(float2 v[8]) {
    float2 t0 = cadd(v[0],v[4]), t4 = csub(v[0],v[4]);
    float2 t1 = cadd(v[1],v[5]), t5 = rotW1<INV>(csub(v[1],v[5]));
    float2 t2 = cadd(v[2],v[6]), t6 = rot90<INV>(csub(v[2],v[6]));
    float2 t3 = cadd(v[3],v[7]), t7 = rotW3<INV>(csub(v[3],v[7]));
    float2 u0 = cadd(t0,t2), u2 = csub(t0,t2);
    float2 u1 = cadd(t1,t3), u3 = rot90<INV>(csub(t1,t3));
    float2 u4 = cadd(t4,t6), u6 = csub(t4,t6);
    float2 u5 = cadd(t5,t7), u7 = rot90<INV>(csub(t5,t7));
    v[0]=cadd(u0,u1); v[4]=csub(u0,u1);
    v[2]=cadd(u2,u3); v[6]=csub(u2,u3);
    v[1]=cadd(u4,u5); v[5]=csub(u4,u5);
    v[3]=cadd(u6,u7); v[7]=csub(u6,u7);
}

__device__ __forceinline__ void apply_pow(float2 v[8], float2 w1) {
    float2 w2 = cmul(w1,w1);
    float2 w3 = cmul(w2,w1);
    float2 w4 = cmul(w2,w2);
    v[1]=cmul(v[1],w1); v[2]=cmul(v[2],w2); v[3]=cmul(v[3],w3); v[4]=cmul(v[4],w4);
    v[5]=cmul(v[5],cmul(w4,w1));
    v[6]=cmul(v[6],cmul(w4,w2));
    v[7]=cmul(v[7],cmul(w4,w3));
}

#define TWO_PI 6.28318530717958647692f

// 512-pt FFT per wave, radix-8. In: v[a]=x[64a+l] natural. Out: reg r = X[64r+l].
// Wave-synchronous: sc is a per-wave 512-float2 scratch, no barriers needed.
__device__ __forceinline__ void fft512_fwd(float2 v[8], int l, float2* sc) {
    int hi = l >> 3, lo = l & 7;
    fft8<0>(v);
    { float s, c; __sincosf(-TWO_PI * (1.0f/512.0f) * (float)l, &s, &c);
      apply_pow(v, make_float2(c, s)); }
#pragma unroll
    for (int q = 0; q < 8; ++q) sc[q*64 + ((hi ^ q) << 3) + lo] = v[q];
#pragma unroll
    for (int b = 0; b < 8; ++b) v[b] = sc[hi*64 + ((b ^ hi) << 3) + lo];
    fft8<0>(v);
    { float s, c; __sincosf(-TWO_PI * (1.0f/64.0f) * (float)lo, &s, &c);
      apply_pow(v, make_float2(c, s)); }
#pragma unroll
    for (int q2 = 0; q2 < 8; ++q2) sc[q2*64 + ((hi ^ q2) << 3) + (lo ^ hi)] = v[q2];
#pragma unroll
    for (int cc = 0; cc < 8; ++cc) v[cc] = sc[hi*64 + ((lo ^ hi) << 3) + (cc ^ lo)];
    fft8<0>(v);
}

__device__ __forceinline__ void fft512_inv(float2 v[8], int l, float2* sc) {
    int hi = l >> 3, lo = l & 7;
    fft8<1>(v);
#pragma unroll
    for (int cc = 0; cc < 8; ++cc) sc[hi*64 + ((lo ^ hi) << 3) + (cc ^ lo)] = v[cc];
#pragma unroll
    for (int q2 = 0; q2 < 8; ++q2) v[q2] = sc[q2*64 + ((hi ^ q2) << 3) + (lo ^ hi)];
    { float s, c; __sincosf(TWO_PI * (1.0f/64.0f) * (float)lo, &s, &c);
      apply_pow(v, make_float2(c, s)); }
    fft8<1>(v);
#pragma unroll
    for (int b = 0; b < 8; ++b) sc[hi*64 + ((b ^ hi) << 3) + lo] = v[b];
#pragma unroll
    for (int q = 0; q < 8; ++q) v[q] = sc[q*64 + ((hi ^ q) << 3) + lo];
    { float s, c; __sincosf(TWO_PI * (1.0f/512.0f) * (float)l, &s, &c);
      apply_pow(v, make_float2(c, s)); }
    fft8<1>(v);
}

// ws layout: spectrum index s = 64r+l is stored at float2 position
//   pos(s) = 128*(r>>1) + 2*l + (r&1)
// so that lane l's 8 registers live at float4 indices {l, 64+l, 128+l, 192+l}.

// ============================ device phase bodies ============================

__device__ __forceinline__ void filt_body(const float* __restrict__ param,
                                          float* __restrict__ filt, int T, int u) {
    int c = T >> 9;
    int vv = T & 511;
    int dh = (u < 256) ? u : (512 - u);
    int dw = (vv < 256) ? vv : (512 - vv);
    int d2 = dh * dh + dw * dw;
    float m = (d2 <= 1) ? 0.5f : fmaxf(1.0f, sqrtf((float)d2) * (2.0f / 256.0f));
    int su  = (u + 256) & 511,  sv  = (vv + 256) & 511;
    int su2 = (256 - u) & 511,  sv2 = (256 - vv) & 511;
    float p  = param[((size_t)c * N + su)  * N + sv];
    float p2 = param[((size_t)c * N + su2) * N + sv2];
    const float invN2 = 1.0f / ((float)N * (float)N);
    int pos = ((vv >> 7) << 7) | ((vv & 63) << 1) | ((vv >> 6) & 1);
    filt[(((size_t)c << 9) + pos) * N + u] = m * 0.5f * (p + p2) * invN2;
}

__device__ __forceinline__ void row_fwd_body(const float* __restrict__ x,
        float2* __restrict__ ws, int pairBase, int pr, int row, int l, float2* myscr) {
    const float* xa = x + ((size_t)(pairBase + pr) * N + row) * N;
    const float* xb = x + ((size_t)(pairBase + pr + NP) * N + row) * N;
    float4 a0 = ((const float4*)xa)[l], a1 = ((const float4*)xa)[64 + l];
    float4 b0 = ((const float4*)xb)[l], b1 = ((const float4*)xb)[64 + l];
    float* s = (float*)myscr;
    ((float4*)s)[l] = a0;       ((float4*)s)[64 + l]  = a1;
    ((float4*)s)[128 + l] = b0; ((float4*)s)[192 + l] = b1;
    float2 v[8];
#pragma unroll
    for (int a = 0; a < 8; ++a) v[a] = make_float2(s[a * 64 + l], s[512 + a * 64 + l]);
    fft512_fwd(v, l, myscr);
    float4* o = (float4*)(ws + ((size_t)pr * N + row) * N);
#pragma unroll
    for (int j = 0; j < 4; ++j)
        o[j * 64 + l] = make_float4(v[2*j].x, v[2*j].y, v[2*j+1].x, v[2*j+1].y);
}

__device__ __forceinline__ void row_inv_body(const float2* __restrict__ ws,
        float* __restrict__ out, int pairBase, int pr, int row, int l, float2* myscr) {
    const float4* i4 = (const float4*)(ws + ((size_t)pr * N + row) * N);
    float4 f0 = i4[l], f1 = i4[64 + l], f2 = i4[128 + l], f3 = i4[192 + l];
    float2 v[8];
    v[0]=make_float2(f0.x,f0.y); v[1]=make_float2(f0.z,f0.w);
    v[2]=make_float2(f1.x,f1.y); v[3]=make_float2(f1.z,f1.w);
    v[4]=make_float2(f2.x,f2.y); v[5]=make_float2(f2.z,f2.w);
    v[6]=make_float2(f3.x,f3.y); v[7]=make_float2(f3.z,f3.w);
    fft512_inv(v, l, myscr);
    float* s = (float*)myscr;
#pragma unroll
    for (int a = 0; a < 8; ++a) { s[a*64 + l] = v[a].x; s[512 + a*64 + l] = v[a].y; }
    float4* oa = (float4*)(out + ((size_t)(pairBase + pr) * N + row) * N);
    float4* ob = (float4*)(out + ((size_t)(pairBase + pr + NP) * N + row) * N);
    oa[l]      = ((float4*)s)[l];
    oa[64 + l] = ((float4*)s)[64 + l];
    ob[l]      = ((float4*)s)[128 + l];
    ob[64 + l] = ((float4*)s)[192 + l];
}

// ===================== fused cooperative kernel (1 dispatch) =================
__global__ __launch_bounds__(512) void k_fused(const float* __restrict__ x,
        const float* __restrict__ param, float* __restrict__ out,
        float2* __restrict__ ws, float* __restrict__ filt,
        int pairBase, int G, int doFilt)
{
    __shared__ float2 smem[8 * CS];          // 32.9 KB: row scratch / col tile
    cg::grid_group grid = cg::this_grid();
    int t = threadIdx.x;
    int l = t & 63, wv = t >> 6;
    float2* myscr = smem + wv * 512;         // per-wave 4 KB slice (row phases)

    // ---- phase 0+1: filter precompute (first chunk) + forward row FFT ----
    if (doFilt) {
        for (int T = blockIdx.x; T < 3 * N; T += gridDim.x)
            filt_body(param, filt, T, t);
    }
    int rowTasks = G << 6;                   // G*512 rows / 8 rows-per-block
    for (int T = blockIdx.x; T < rowTasks; T += gridDim.x)
        row_fwd_body(x, ws, pairBase, T >> 6, ((T & 63) << 3) + wv, l, myscr);

    __threadfence();
    grid.sync();

    // ---- phase 2: column FFT -> filter -> column IFFT ----
    for (int T = blockIdx.x; T < rowTasks; T += gridDim.x) {
        int pr = T >> 6;
        int colBase = (T & 63) << 3;
        float2* wsImg = ws + (size_t)pr * (size_t)(N * N);
        __syncthreads();                     // protect tile reuse across iterations

        float4 g4[4];
#pragma unroll
        for (int k = 0; k < 4; ++k) {
            int lin = (k << 10) + (t << 1);
            int r = lin >> 3, c = lin & 7;
            g4[k] = *(const float4*)(&wsImg[(size_t)r * N + colBase + c]);
        }
#pragma unroll
        for (int k = 0; k < 4; ++k) {
            int lin = (k << 10) + (t << 1);
            int r = lin >> 3, c = lin & 7;
            smem[c * CS + r]       = make_float2(g4[k].x, g4[k].y);
            smem[(c + 1) * CS + r] = make_float2(g4[k].z, g4[k].w);
        }
        __syncthreads();

        float2* sc = smem + wv * CS;
        float2 v[8];
#pragma unroll
        for (int a = 0; a < 8; ++a) v[a] = sc[a * 64 + l];

        fft512_fwd(v, l, sc);

        int ch = (pairBase + pr) % 3;
        int col = colBase + wv;
        const float* fcol = filt + (((size_t)ch << 9) + col) * N;
#pragma unroll
        for (int r = 0; r < 8; ++r) {
            float f = fcol[r * 64 + l];
            v[r].x *= f; v[r].y *= f;
        }

        fft512_inv(v, l, sc);

#pragma unroll
        for (int a = 0; a < 8; ++a) sc[a * 64 + l] = v[a];
        __syncthreads();

#pragma unroll
        for (int k = 0; k < 4; ++k) {
            int lin = (k << 10) + (t << 1);
            int r = lin >> 3, c = lin & 7;
            float2 e0 = smem[c * CS + r], e1 = smem[(c + 1) * CS + r];
            g4[k] = make_float4(e0.x, e0.y, e1.x, e1.y);
        }
#pragma unroll
        for (int k = 0; k < 4; ++k) {
            int lin = (k << 10) + (t << 1);
            int r = lin >> 3, c = lin & 7;
            *(float4*)(&wsImg[(size_t)r * N + colBase + c]) = g4[k];
        }
    }

    __threadfence();
    grid.sync();

    // ---- phase 3: inverse row FFT ----
    for (int T = blockIdx.x; T < rowTasks; T += gridDim.x)
        row_inv_body(ws, out, pairBase, T >> 6, ((T & 63) << 3) + wv, l, myscr);
}

// ===================== fallback classic kernels (4 dispatches) ===============
__global__ __launch_bounds__(512) void k_filt(const float* __restrict__ param,
                                              float* __restrict__ filt) {
    filt_body(param, filt, blockIdx.x, threadIdx.x);
}

__global__ __launch_bounds__(256) void k_row_fwd(const float* __restrict__ x,
                                                 float2* __restrict__ ws, int pairBase) {
    __shared__ float2 scr[4 * 512];
    int t = threadIdx.x;
    int l = t & 63, wv = t >> 6;
    int pr = blockIdx.x >> 7;
    int row = ((blockIdx.x & 127) << 2) + wv;
    row_fwd_body(x, ws, pairBase, pr, row, l, scr + wv * 512);
}

__global__ __launch_bounds__(512) void k_col(float2* __restrict__ ws,
                                             const float* __restrict__ filt, int pairBase) {
    __shared__ float2 tile[8 * CS];
    int t = threadIdx.x;
    int l = t & 63, wv = t >> 6;
    int pr = blockIdx.x >> 6;
    int colBase = (blockIdx.x & 63) << 3;
    float2* wsImg = ws + (size_t)pr * (size_t)(N * N);

    float4 g4[4];
#pragma unroll
    for (int k = 0; k < 4; ++k) {
        int lin = (k << 10) + (t << 1);
        int r = lin >> 3, c = lin & 7;
        g4[k] = *(const float4*)(&wsImg[(size_t)r * N + colBase + c]);
    }
#pragma unroll
    for (int k = 0; k < 4; ++k) {
        int lin = (k << 10) + (t << 1);
        int r = lin >> 3, c = lin & 7;
        tile[c * CS + r]       = make_float2(g4[k].x, g4[k].y);
        tile[(c + 1) * CS + r] = make_float2(g4[k].z, g4[k].w);
    }
    __syncthreads();

    float2* sc = tile + wv * CS;
    float2 v[8];
#pragma unroll
    for (int a = 0; a < 8; ++a) v[a] = sc[a * 64 + l];
    fft512_fwd(v, l, sc);

    int ch = (pairBase + pr) % 3;
    int col = colBase + wv;
    const float* fcol = filt + (((size_t)ch << 9) + col) * N;
#pragma unroll
    for (int r = 0; r < 8; ++r) {
        float f = fcol[r * 64 + l];
        v[r].x *= f; v[r].y *= f;
    }
    fft512_inv(v, l, sc);

#pragma unroll
    for (int a = 0; a < 8; ++a) sc[a * 64 + l] = v[a];
    __syncthreads();

#pragma unroll
    for (int k = 0; k < 4; ++k) {
        int lin = (k << 10) + (t << 1);
        int r = lin >> 3, c = lin & 7;
        float2 e0 = tile[c * CS + r], e1 = tile[(c + 1) * CS + r];
        g4[k] = make_float4(e0.x, e0.y, e1.x, e1.y);
    }
#pragma unroll
    for (int k = 0; k < 4; ++k) {
        int lin = (k << 10) + (t << 1);
        int r = lin >> 3, c = lin & 7;
        *(float4*)(&wsImg[(size_t)r * N + colBase + c]) = g4[k];
    }
}

__global__ __launch_bounds__(256) void k_row_inv(const float2* __restrict__ ws,
                                                 float* __restrict__ out, int pairBase) {
    __shared__ float2 scr[4 * 512];
    int t = threadIdx.x;
    int l = t & 63, wv = t >> 6;
    int pr = blockIdx.x >> 7;
    int row = ((blockIdx.x & 127) << 2) + wv;
    row_inv_body(ws, out, pairBase, pr, row, l, scr + wv * 512);
}

extern "C" void kernel_launch(void* const* d_in, const int* in_sizes, int n_in,
                              void* d_out, int out_size, void* d_ws, size_t ws_size,
                              hipStream_t stream) {
    const float* x = (const float*)d_in[0];
    const float* param = (const float*)d_in[1];
    float* out = (float*)d_out;

    float* filt = (float*)d_ws;                       // 3*512*512 floats = 3 MB
    const size_t filtElems = (size_t)3 * N * N;
    float2* ws = (float2*)((char*)d_ws + filtElems * sizeof(float));

    size_t perImg = (size_t)N * N * sizeof(float2);   // 2 MB per pair
    size_t avail = (ws_size > filtElems * sizeof(float)) ? ws_size - filtElems * sizeof(float) : 0;
    int G = (int)(avail / perImg);
    if (G < 1) G = 1;
    if (G > NP) G = NP;

    // grid size for the cooperative launch: all blocks resident, once per process
    static int nblk = 0;
    if (nblk == 0) {
        int perCU = 0;
        if (hipOccupancyMaxActiveBlocksPerMultiprocessor(&perCU, k_fused, 512, 0) != hipSuccess
            || perCU < 1) perCU = 1;
        int cus = 256;
        int dev = 0;
        hipDeviceProp_t prop;
        if (hipGetDevice(&dev) == hipSuccess &&
            hipGetDeviceProperties(&prop, dev) == hipSuccess &&
            prop.multiProcessorCount > 0)
            cus = prop.multiProcessorCount;
        long total = (long)perCU * (long)cus;
        if (total > 3072) total = 3072;
        if (total < 1) total = 1;
        nblk = (int)total;
    }

    bool coopOK = true;
    for (int base = 0; base < NP && coopOK; base += G) {
        int g = NP - base;
        if (g > G) g = G;
        int doFilt = (base == 0) ? 1 : 0;
        void* args[] = { (void*)&x, (void*)&param, (void*)&out,
                         (void*)&ws, (void*)&filt, (void*)&base, (void*)&g, (void*)&doFilt };
        hipError_t err = hipLaunchCooperativeKernel((const void*)k_fused,
                                                    dim3(nblk), dim3(512),
                                                    args, 0, stream);
        if (err != hipSuccess) { coopOK = false; break; }
    }

    if (!coopOK) {
        // fallback: classic 4-dispatch path (proven correct at 272-279 us)
        k_filt<<<dim3(3 * N), dim3(N), 0, stream>>>(param, filt);
        for (int base = 0; base < NP; base += G) {
            int g = NP - base;
            if (g > G) g = G;
            k_row_fwd<<<dim3(g * 128), dim3(256), 0, stream>>>(x, ws, base);
            k_col<<<dim3(g * 64), dim3(512), 0, stream>>>(ws, filt, base);
            k_row_inv<<<dim3(g * 128), dim3(256), 0, stream>>>(ws, out, base);
        }
    }
}

// Round 8
// 277.667 us; speedup vs baseline: 1.7510x; 1.7510x over previous
//
#include <hip/hip_runtime.h>
#include <math.h>

#define N 512
#define CS 514
#define S8 0.70710678118654752440f

__device__ __forceinline__ float2 cadd(float2 a, float2 b){ return make_float2(a.x+b.x, a.y+b.y); }
__device__ __forceinline__ float2 csub(float2 a, float2 b){ return make_float2(a.x-b.x, a.y-b.y); }
__device__ __forceinline__ float2 cmul(float2 a, float2 b){
    return make_float2(fmaf(a.x,b.x,-(a.y*b.y)), fmaf(a.x,b.y, a.y*b.x));
}
template<int INV> __device__ __forceinline__ float2 rot90(float2 a){
    return INV ? make_float2(-a.y, a.x) : make_float2(a.y, -a.x);          // *(∓i)
}
template<int INV> __device__ __forceinline__ float2 rotW1(float2 a){       // *W8^{±1}
    return INV ? make_float2(S8*(a.x-a.y), S8*(a.x+a.y))
               : make_float2(S8*(a.x+a.y), S8*(a.y-a.x));
}
template<int INV> __device__ __forceinline__ float2 rotW3(float2 a){       // *W8^{±3}
    return INV ? make_float2(-S8*(a.x+a.y), S8*(a.x-a.y))
               : make_float2(S8*(a.y-a.x), -S8*(a.x+a.y));
}

template<int INV>
__device__ __forceinline__ void fft8(float2 v[8]) {
    float2 t0 = cadd(v[0],v[4]), t4 = csub(v[0],v[4]);
    float2 t1 = cadd(v[1],v[5]), t5 = rotW1<INV>(csub(v[1],v[5]));
    float2 t2 = cadd(v[2],v[6]), t6 = rot90<INV>(csub(v[2],v[6]));
    float2 t3 = cadd(v[3],v[7]), t7 = rotW3<INV>(csub(v[3],v[7]));
    float2 u0 = cadd(t0,t2), u2 = csub(t0,t2);
    float2 u1 = cadd(t1,t3), u3 = rot90<INV>(csub(t1,t3));
    float2 u4 = cadd(t4,t6), u6 = csub(t4,t6);
    float2 u5 = cadd(t5,t7), u7 = rot90<INV>(csub(t5,t7));
    v[0]=cadd(u0,u1); v[4]=csub(u0,u1);
    v[2]=cadd(u2,u3); v[6]=csub(u2,u3);
    v[1]=cadd(u4,u5); v[5]=csub(u4,u5);
    v[3]=cadd(u6,u7); v[7]=csub(u6,u7);
}

__device__ __forceinline__ void apply_pow(float2 v[8], float2 w1) {
    float2 w2 = cmul(w1,w1);
    float2 w3 = cmul(w2,w1);
    float2 w4 = cmul(w2,w2);
    v[1]=cmul(v[1],w1); v[2]=cmul(v[2],w2); v[3]=cmul(v[3],w3); v[4]=cmul(v[4],w4);
    v[5]=cmul(v[5],cmul(w4,w1));
    v[6]=cmul(v[6],cmul(w4,w2));
    v[7]=cmul(v[7],cmul(w4,w3));
}

#define TWO_PI 6.28318530717958647692f

// 512-pt FFT per wave, radix-8. In: v[a]=x[64a+l] natural. Out: reg r = X[64r+l].
// Wave-synchronous: sc is a per-wave 512-float2 scratch, no barriers needed.
__device__ __forceinline__ void fft512_fwd(float2 v[8], int l, float2* sc) {
    int hi = l >> 3, lo = l & 7;
    fft8<0>(v);
    { float s, c; __sincosf(-TWO_PI * (1.0f/512.0f) * (float)l, &s, &c);
      apply_pow(v, make_float2(c, s)); }
#pragma unroll
    for (int q = 0; q < 8; ++q) sc[q*64 + ((hi ^ q) << 3) + lo] = v[q];
#pragma unroll
    for (int b = 0; b < 8; ++b) v[b] = sc[hi*64 + ((b ^ hi) << 3) + lo];
    fft8<0>(v);
    { float s, c; __sincosf(-TWO_PI * (1.0f/64.0f) * (float)lo, &s, &c);
      apply_pow(v, make_float2(c, s)); }
#pragma unroll
    for (int q2 = 0; q2 < 8; ++q2) sc[q2*64 + ((hi ^ q2) << 3) + (lo ^ hi)] = v[q2];
#pragma unroll
    for (int cc = 0; cc < 8; ++cc) v[cc] = sc[hi*64 + ((lo ^ hi) << 3) + (cc ^ lo)];
    fft8<0>(v);
}

__device__ __forceinline__ void fft512_inv(float2 v[8], int l, float2* sc) {
    int hi = l >> 3, lo = l & 7;
    fft8<1>(v);
#pragma unroll
    for (int cc = 0; cc < 8; ++cc) sc[hi*64 + ((lo ^ hi) << 3) + (cc ^ lo)] = v[cc];
#pragma unroll
    for (int q2 = 0; q2 < 8; ++q2) v[q2] = sc[q2*64 + ((hi ^ q2) << 3) + (lo ^ hi)];
    { float s, c; __sincosf(TWO_PI * (1.0f/64.0f) * (float)lo, &s, &c);
      apply_pow(v, make_float2(c, s)); }
    fft8<1>(v);
#pragma unroll
    for (int b = 0; b < 8; ++b) sc[hi*64 + ((b ^ hi) << 3) + lo] = v[b];
#pragma unroll
    for (int q = 0; q < 8; ++q) v[q] = sc[q*64 + ((hi ^ q) << 3) + lo];
    { float s, c; __sincosf(TWO_PI * (1.0f/512.0f) * (float)l, &s, &c);
      apply_pow(v, make_float2(c, s)); }
    fft8<1>(v);
}

// ws layout: spectrum index s = 64r+l is stored at float2 position
//   pos(s) = 128*(r>>1) + 2*l + (r&1)
// so that lane l's 8 registers live at float4 indices {l, 64+l, 128+l, 192+l}.

// -------- Kernel 0: precompute symmetrized filter, permuted-column layout ----
__global__ __launch_bounds__(512) void k_filt(const float* __restrict__ param,
                                              float* __restrict__ filt) {
    int c = blockIdx.x >> 9;
    int vv = blockIdx.x & 511;
    int u = threadIdx.x;
    int dh = (u < 256) ? u : (512 - u);
    int dw = (vv < 256) ? vv : (512 - vv);
    int d2 = dh * dh + dw * dw;
    float m = (d2 <= 1) ? 0.5f : fmaxf(1.0f, sqrtf((float)d2) * (2.0f / 256.0f));
    int su  = (u + 256) & 511,  sv  = (vv + 256) & 511;
    int su2 = (256 - u) & 511,  sv2 = (256 - vv) & 511;
    float p  = param[((size_t)c * N + su)  * N + sv];
    float p2 = param[((size_t)c * N + su2) * N + sv2];
    const float invN2 = 1.0f / ((float)N * (float)N);
    int pos = ((vv >> 7) << 7) | ((vv & 63) << 1) | ((vv >> 6) & 1);
    filt[(((size_t)c << 9) + pos) * N + u] = m * 0.5f * (p + p2) * invN2;
}

// -------- Kernel 1: forward row FFT of packed pair (A + iB). 4 rows/block. ---
// No barriers: per-wave scratch, twiddles computed inline.
__global__ __launch_bounds__(256) void k_row_fwd(const float* __restrict__ x,
                                                 float2* __restrict__ ws, int pairBase) {
    __shared__ float2 scr[4 * 512];
    int t = threadIdx.x;
    int l = t & 63, wv = t >> 6;
    int pr = blockIdx.x >> 7;               // pair within chunk
    int row = ((blockIdx.x & 127) << 2) + wv;
    int pair = pairBase + pr;               // imgA = pair, imgB = pair + 48 (same channel)
    const float4* xa = (const float4*)(x + ((size_t)pair * N + row) * N);
    const float4* xb = (const float4*)(x + ((size_t)(pair + 48) * N + row) * N);
    float4 a0 = xa[l], a1 = xa[64 + l];
    float4 b0 = xb[l], b1 = xb[64 + l];
    float* s = (float*)(scr + wv * 512);    // 1024 floats: [0,512)=A row, [512,1024)=B row
    ((float4*)s)[l] = a0;       ((float4*)s)[64 + l]  = a1;
    ((float4*)s)[128 + l] = b0; ((float4*)s)[192 + l] = b1;
    float2 v[8];
#pragma unroll
    for (int a = 0; a < 8; ++a) v[a] = make_float2(s[a * 64 + l], s[512 + a * 64 + l]);
    fft512_fwd(v, l, scr + wv * 512);
    float4* o = (float4*)(ws + ((size_t)pr * N + row) * N);
#pragma unroll
    for (int j = 0; j < 4; ++j)
        o[j * 64 + l] = make_float4(v[2*j].x, v[2*j].y, v[2*j+1].x, v[2*j+1].y);
}

// -------- Kernel 2: column FFT -> filter -> column IFFT. 512 thr, 8 cols. ----
__global__ __launch_bounds__(512) void k_col(float2* __restrict__ ws,
                                             const float* __restrict__ filt, int pairBase) {
    __shared__ float2 tile[8 * CS];
    int t = threadIdx.x;
    int l = t & 63, wv = t >> 6;
    int pr = blockIdx.x >> 6;
    int colBase = (blockIdx.x & 63) << 3;
    float2* wsImg = ws + (size_t)pr * (size_t)(N * N);

    float4 g[4];
#pragma unroll
    for (int k = 0; k < 4; ++k) {
        int lin = (k << 10) + (t << 1);     // float2 linear index, even
        int r = lin >> 3, c = lin & 7;      // c in {0,2,4,6}
        g[k] = *(const float4*)(&wsImg[(size_t)r * N + colBase + c]);
    }
#pragma unroll
    for (int k = 0; k < 4; ++k) {
        int lin = (k << 10) + (t << 1);
        int r = lin >> 3, c = lin & 7;
        tile[c * CS + r]       = make_float2(g[k].x, g[k].y);
        tile[(c + 1) * CS + r] = make_float2(g[k].z, g[k].w);
    }
    __syncthreads();

    float2* sc = tile + wv * CS;
    float2 v[8];
#pragma unroll
    for (int a = 0; a < 8; ++a) v[a] = sc[a * 64 + l];

    fft512_fwd(v, l, sc);

    int ch = (pairBase + pr) % 3;
    int col = colBase + wv;
    const float* fcol = filt + (((size_t)ch << 9) + col) * N;
#pragma unroll
    for (int r = 0; r < 8; ++r) {
        float f = fcol[r * 64 + l];
        v[r].x *= f; v[r].y *= f;
    }

    fft512_inv(v, l, sc);

#pragma unroll
    for (int a = 0; a < 8; ++a) sc[a * 64 + l] = v[a];
    __syncthreads();

#pragma unroll
    for (int k = 0; k < 4; ++k) {
        int lin = (k << 10) + (t << 1);
        int r = lin >> 3, c = lin & 7;
        float2 e0 = tile[c * CS + r], e1 = tile[(c + 1) * CS + r];
        g[k] = make_float4(e0.x, e0.y, e1.x, e1.y);
    }
#pragma unroll
    for (int k = 0; k < 4; ++k) {
        int lin = (k << 10) + (t << 1);
        int r = lin >> 3, c = lin & 7;
        *(float4*)(&wsImg[(size_t)r * N + colBase + c]) = g[k];
    }
}

// -------- Kernel 3: inverse row FFT; Re -> imgA, Im -> imgB. 4 rows/block. ---
__global__ __launch_bounds__(256) void k_row_inv(const float2* __restrict__ ws,
                                                 float* __restrict__ out, int pairBase) {
    __shared__ float2 scr[4 * 512];
    int t = threadIdx.x;
    int l = t & 63, wv = t >> 6;
    int pr = blockIdx.x >> 7;
    int row = ((blockIdx.x & 127) << 2) + wv;
    int pair = pairBase + pr;
    const float4* i4 = (const float4*)(ws + ((size_t)pr * N + row) * N);
    float2 v[8];
#pragma unroll
    for (int j = 0; j < 4; ++j) {
        float4 f = i4[j * 64 + l];
        v[2*j]   = make_float2(f.x, f.y);
        v[2*j+1] = make_float2(f.z, f.w);
    }
    fft512_inv(v, l, scr + wv * 512);
    float* s = (float*)(scr + wv * 512);    // [0,512)=Re row, [512,1024)=Im row
#pragma unroll
    for (int a = 0; a < 8; ++a) { s[a*64 + l] = v[a].x; s[512 + a*64 + l] = v[a].y; }
    float4* oa = (float4*)(out + ((size_t)pair * N + row) * N);
    float4* ob = (float4*)(out + ((size_t)(pair + 48) * N + row) * N);
    oa[l]      = ((float4*)s)[l];
    oa[64 + l] = ((float4*)s)[64 + l];
    ob[l]      = ((float4*)s)[128 + l];
    ob[64 + l] = ((float4*)s)[192 + l];
}

extern "C" void kernel_launch(void* const* d_in, const int* in_sizes, int n_in,
                              void* d_out, int out_size, void* d_ws, size_t ws_size,
                              hipStream_t stream) {
    const float* x = (const float*)d_in[0];
    const float* param = (const float*)d_in[1];
    float* out = (float*)d_out;

    float* filt = (float*)d_ws;                       // 3*512*512 floats = 3 MB
    const size_t filtElems = (size_t)3 * N * N;
    float2* ws = (float2*)((char*)d_ws + filtElems * sizeof(float));

    const int NP = 48;                                // image pairs (A=i, B=i+48)
    size_t perImg = (size_t)N * N * sizeof(float2);   // 2 MB per pair
    size_t avail = (ws_size > filtElems * sizeof(float)) ? ws_size - filtElems * sizeof(float) : 0;
    int G = (int)(avail / perImg);
    if (G < 1) G = 1;
    // L3-locality chunking: cap the chunk so one row_fwd->col->row_inv cycle's
    // working set (ws 2G MB + x 2G MB + out 2G MB) stays inside the 256 MB
    // Infinity Cache. G=24 -> ~144 MB cycle, col/inv ws reads become L3 hits.
    if (G > 24) G = 24;
    if (G > NP) G = NP;

    k_filt<<<dim3(3 * N), dim3(N), 0, stream>>>(param, filt);

    for (int base = 0; base < NP; base += G) {
        int g = NP - base;
        if (g > G) g = G;
        k_row_fwd<<<dim3(g * 128), dim3(256), 0, stream>>>(x, ws, base);
        k_col<<<dim3(g * 64), dim3(512), 0, stream>>>(ws, filt, base);
        k_row_inv<<<dim3(g * 128), dim3(256), 0, stream>>>(ws, out, base);
    }
}

// Round 9
// 262.270 us; speedup vs baseline: 1.8537x; 1.0587x over previous
//
#include <hip/hip_runtime.h>
#include <hip/hip_fp16.h>
#include <math.h>

#define N 512
#define CS 514
#define S8 0.70710678118654752440f

struct alignas(16) H2x4 { __half2 h[4]; };   // 4 fp16 complex = 16 B

__device__ __forceinline__ float2 cadd(float2 a, float2 b){ return make_float2(a.x+b.x, a.y+b.y); }
__device__ __forceinline__ float2 csub(float2 a, float2 b){ return make_float2(a.x-b.x, a.y-b.y); }
__device__ __forceinline__ float2 cmul(float2 a, float2 b){
    return make_float2(fmaf(a.x,b.x,-(a.y*b.y)), fmaf(a.x,b.y, a.y*b.x));
}
template<int INV> __device__ __forceinline__ float2 rot90(float2 a){
    return INV ? make_float2(-a.y, a.x) : make_float2(a.y, -a.x);          // *(∓i)
}
template<int INV> __device__ __forceinline__ float2 rotW1(float2 a){       // *W8^{±1}
    return INV ? make_float2(S8*(a.x-a.y), S8*(a.x+a.y))
               : make_float2(S8*(a.x+a.y), S8*(a.y-a.x));
}
template<int INV> __device__ __forceinline__ float2 rotW3(float2 a){       // *W8^{±3}
    return INV ? make_float2(-S8*(a.x+a.y), S8*(a.x-a.y))
               : make_float2(S8*(a.y-a.x), -S8*(a.x+a.y));
}

template<int INV>
__device__ __forceinline__ void fft8(float2 v[8]) {
    float2 t0 = cadd(v[0],v[4]), t4 = csub(v[0],v[4]);
    float2 t1 = cadd(v[1],v[5]), t5 = rotW1<INV>(csub(v[1],v[5]));
    float2 t2 = cadd(v[2],v[6]), t6 = rot90<INV>(csub(v[2],v[6]));
    float2 t3 = cadd(v[3],v[7]), t7 = rotW3<INV>(csub(v[3],v[7]));
    float2 u0 = cadd(t0,t2), u2 = csub(t0,t2);
    float2 u1 = cadd(t1,t3), u3 = rot90<INV>(csub(t1,t3));
    float2 u4 = cadd(t4,t6), u6 = csub(t4,t6);
    float2 u5 = cadd(t5,t7), u7 = rot90<INV>(csub(t5,t7));
    v[0]=cadd(u0,u1); v[4]=csub(u0,u1);
    v[2]=cadd(u2,u3); v[6]=csub(u2,u3);
    v[1]=cadd(u4,u5); v[5]=csub(u4,u5);
    v[3]=cadd(u6,u7); v[7]=csub(u6,u7);
}

__device__ __forceinline__ void apply_pow(float2 v[8], float2 w1) {
    float2 w2 = cmul(w1,w1);
    float2 w3 = cmul(w2,w1);
    float2 w4 = cmul(w2,w2);
    v[1]=cmul(v[1],w1); v[2]=cmul(v[2],w2); v[3]=cmul(v[3],w3); v[4]=cmul(v[4],w4);
    v[5]=cmul(v[5],cmul(w4,w1));
    v[6]=cmul(v[6],cmul(w4,w2));
    v[7]=cmul(v[7],cmul(w4,w3));
}

#define TWO_PI 6.28318530717958647692f

// 512-pt FFT per wave, radix-8. In: v[a]=x[64a+l] natural. Out: reg r = X[64r+l].
// Wave-synchronous: sc is a per-wave 512-float2 scratch, no barriers needed.
__device__ __forceinline__ void fft512_fwd(float2 v[8], int l, float2* sc) {
    int hi = l >> 3, lo = l & 7;
    fft8<0>(v);
    { float s, c; __sincosf(-TWO_PI * (1.0f/512.0f) * (float)l, &s, &c);
      apply_pow(v, make_float2(c, s)); }
#pragma unroll
    for (int q = 0; q < 8; ++q) sc[q*64 + ((hi ^ q) << 3) + lo] = v[q];
#pragma unroll
    for (int b = 0; b < 8; ++b) v[b] = sc[hi*64 + ((b ^ hi) << 3) + lo];
    fft8<0>(v);
    { float s, c; __sincosf(-TWO_PI * (1.0f/64.0f) * (float)lo, &s, &c);
      apply_pow(v, make_float2(c, s)); }
#pragma unroll
    for (int q2 = 0; q2 < 8; ++q2) sc[q2*64 + ((hi ^ q2) << 3) + (lo ^ hi)] = v[q2];
#pragma unroll
    for (int cc = 0; cc < 8; ++cc) v[cc] = sc[hi*64 + ((lo ^ hi) << 3) + (cc ^ lo)];
    fft8<0>(v);
}

__device__ __forceinline__ void fft512_inv(float2 v[8], int l, float2* sc) {
    int hi = l >> 3, lo = l & 7;
    fft8<1>(v);
#pragma unroll
    for (int cc = 0; cc < 8; ++cc) sc[hi*64 + ((lo ^ hi) << 3) + (cc ^ lo)] = v[cc];
#pragma unroll
    for (int q2 = 0; q2 < 8; ++q2) v[q2] = sc[q2*64 + ((hi ^ q2) << 3) + (lo ^ hi)];
    { float s, c; __sincosf(TWO_PI * (1.0f/64.0f) * (float)lo, &s, &c);
      apply_pow(v, make_float2(c, s)); }
    fft8<1>(v);
#pragma unroll
    for (int b = 0; b < 8; ++b) sc[hi*64 + ((b ^ hi) << 3) + lo] = v[b];
#pragma unroll
    for (int q = 0; q < 8; ++q) v[q] = sc[q*64 + ((hi ^ q) << 3) + lo];
    { float s, c; __sincosf(TWO_PI * (1.0f/512.0f) * (float)l, &s, &c);
      apply_pow(v, make_float2(c, s)); }
    fft8<1>(v);
}

// fp16 ws layout: spectrum index s = 64r+l is stored at complex position
//   pos(s) = 256*(r>>2) + 4*l + (r&3)
// so lane l's 8 registers are two contiguous 16B H2x4 chunks at chunk
// indices {l, 64+l} -> every ws access is a full lane-coalesced 16B op.

// -------- Kernel 0: precompute symmetrized filter, permuted-column layout ----
__global__ __launch_bounds__(512) void k_filt(const float* __restrict__ param,
                                              float* __restrict__ filt) {
    int c = blockIdx.x >> 9;
    int vv = blockIdx.x & 511;
    int u = threadIdx.x;
    int dh = (u < 256) ? u : (512 - u);
    int dw = (vv < 256) ? vv : (512 - vv);
    int d2 = dh * dh + dw * dw;
    float m = (d2 <= 1) ? 0.5f : fmaxf(1.0f, sqrtf((float)d2) * (2.0f / 256.0f));
    int su  = (u + 256) & 511,  sv  = (vv + 256) & 511;
    int su2 = (256 - u) & 511,  sv2 = (256 - vv) & 511;
    float p  = param[((size_t)c * N + su)  * N + sv];
    float p2 = param[((size_t)c * N + su2) * N + sv2];
    const float invN2 = 1.0f / ((float)N * (float)N);
    int pos = ((vv >> 8) << 8) | ((vv & 63) << 2) | ((vv >> 6) & 3);
    filt[(((size_t)c << 9) + pos) * N + u] = m * 0.5f * (p + p2) * invN2;
}

// -------- Kernel 1: forward row FFT of packed pair (A + iB). 4 rows/block. ---
__global__ __launch_bounds__(256) void k_row_fwd(const float* __restrict__ x,
                                                 __half2* __restrict__ ws, int pairBase) {
    __shared__ float2 scr[4 * 512];
    int t = threadIdx.x;
    int l = t & 63, wv = t >> 6;
    int pr = blockIdx.x >> 7;               // pair within chunk
    int row = ((blockIdx.x & 127) << 2) + wv;
    int pair = pairBase + pr;               // imgA = pair, imgB = pair + 48 (same channel)
    const float4* xa = (const float4*)(x + ((size_t)pair * N + row) * N);
    const float4* xb = (const float4*)(x + ((size_t)(pair + 48) * N + row) * N);
    float4 a0 = xa[l], a1 = xa[64 + l];
    float4 b0 = xb[l], b1 = xb[64 + l];
    float* s = (float*)(scr + wv * 512);    // 1024 floats: [0,512)=A row, [512,1024)=B row
    ((float4*)s)[l] = a0;       ((float4*)s)[64 + l]  = a1;
    ((float4*)s)[128 + l] = b0; ((float4*)s)[192 + l] = b1;
    float2 v[8];
#pragma unroll
    for (int a = 0; a < 8; ++a) v[a] = make_float2(s[a * 64 + l], s[512 + a * 64 + l]);
    fft512_fwd(v, l, scr + wv * 512);
    H2x4* o = (H2x4*)(ws + ((size_t)pr * N + row) * N);
#pragma unroll
    for (int k2 = 0; k2 < 2; ++k2) {
        H2x4 tmp;
#pragma unroll
        for (int b = 0; b < 4; ++b)
            tmp.h[b] = __float22half2_rn(make_float2(v[4*k2+b].x, v[4*k2+b].y));
        o[k2 * 64 + l] = tmp;
    }
}

// -------- Kernel 2: column FFT -> filter -> column IFFT. 512 thr, 8 cols. ----
__global__ __launch_bounds__(512) void k_col(__half2* __restrict__ ws,
                                             const float* __restrict__ filt, int pairBase) {
    __shared__ float2 tile[8 * CS];
    int t = threadIdx.x;
    int l = t & 63, wv = t >> 6;
    int pr = blockIdx.x >> 6;
    int colBase = (blockIdx.x & 63) << 3;
    __half2* wsImg = ws + (size_t)pr * (size_t)(N * N);

    H2x4 g[2];
#pragma unroll
    for (int k = 0; k < 2; ++k) {
        int q = (k << 9) + t;               // 16B-chunk index within tile, 0..1023
        int r = q >> 1, h = (q & 1) << 2;   // row, col-subchunk (0 or 4)
        g[k] = *(const H2x4*)(&wsImg[(size_t)r * N + colBase + h]);
    }
#pragma unroll
    for (int k = 0; k < 2; ++k) {
        int q = (k << 9) + t;
        int r = q >> 1, h = (q & 1) << 2;
#pragma unroll
        for (int b = 0; b < 4; ++b)
            tile[(h + b) * CS + r] = __half22float2(g[k].h[b]);
    }
    __syncthreads();

    float2* sc = tile + wv * CS;
    float2 v[8];
#pragma unroll
    for (int a = 0; a < 8; ++a) v[a] = sc[a * 64 + l];

    fft512_fwd(v, l, sc);

    int ch = (pairBase + pr) % 3;
    int col = colBase + wv;
    const float* fcol = filt + (((size_t)ch << 9) + col) * N;
#pragma unroll
    for (int r = 0; r < 8; ++r) {
        float f = fcol[r * 64 + l];
        v[r].x *= f; v[r].y *= f;
    }

    fft512_inv(v, l, sc);

#pragma unroll
    for (int a = 0; a < 8; ++a) sc[a * 64 + l] = v[a];
    __syncthreads();

#pragma unroll
    for (int k = 0; k < 2; ++k) {
        int q = (k << 9) + t;
        int r = q >> 1, h = (q & 1) << 2;
        H2x4 w;
#pragma unroll
        for (int b = 0; b < 4; ++b)
            w.h[b] = __float22half2_rn(tile[(h + b) * CS + r]);
        *(H2x4*)(&wsImg[(size_t)r * N + colBase + h]) = w;
    }
}

// -------- Kernel 3: inverse row FFT; Re -> imgA, Im -> imgB. 4 rows/block. ---
__global__ __launch_bounds__(256) void k_row_inv(const __half2* __restrict__ ws,
                                                 float* __restrict__ out, int pairBase) {
    __shared__ float2 scr[4 * 512];
    int t = threadIdx.x;
    int l = t & 63, wv = t >> 6;
    int pr = blockIdx.x >> 7;
    int row = ((blockIdx.x & 127) << 2) + wv;
    int pair = pairBase + pr;
    const H2x4* i4 = (const H2x4*)(ws + ((size_t)pr * N + row) * N);
    float2 v[8];
#pragma unroll
    for (int k2 = 0; k2 < 2; ++k2) {
        H2x4 g = i4[k2 * 64 + l];
#pragma unroll
        for (int b = 0; b < 4; ++b)
            v[4*k2+b] = __half22float2(g.h[b]);
    }
    fft512_inv(v, l, scr + wv * 512);
    float* s = (float*)(scr + wv * 512);    // [0,512)=Re row, [512,1024)=Im row
#pragma unroll
    for (int a = 0; a < 8; ++a) { s[a*64 + l] = v[a].x; s[512 + a*64 + l] = v[a].y; }
    float4* oa = (float4*)(out + ((size_t)pair * N + row) * N);
    float4* ob = (float4*)(out + ((size_t)(pair + 48) * N + row) * N);
    oa[l]      = ((float4*)s)[l];
    oa[64 + l] = ((float4*)s)[64 + l];
    ob[l]      = ((float4*)s)[128 + l];
    ob[64 + l] = ((float4*)s)[192 + l];
}

extern "C" void kernel_launch(void* const* d_in, const int* in_sizes, int n_in,
                              void* d_out, int out_size, void* d_ws, size_t ws_size,
                              hipStream_t stream) {
    const float* x = (const float*)d_in[0];
    const float* param = (const float*)d_in[1];
    float* out = (float*)d_out;

    float* filt = (float*)d_ws;                       // 3*512*512 floats = 3 MB
    const size_t filtElems = (size_t)3 * N * N;
    __half2* ws = (__half2*)((char*)d_ws + filtElems * sizeof(float));

    const int NP = 48;                                // image pairs (A=i, B=i+48)
    size_t perImg = (size_t)N * N * sizeof(__half2);  // 1 MB per pair (fp16 complex)
    size_t avail = (ws_size > filtElems * sizeof(float)) ? ws_size - filtElems * sizeof(float) : 0;
    int G = (int)(avail / perImg);
    if (G < 1) G = 1;
    if (G > NP) G = NP;

    k_filt<<<dim3(3 * N), dim3(N), 0, stream>>>(param, filt);

    for (int base = 0; base < NP; base += G) {
        int g = NP - base;
        if (g > G) g = G;
        k_row_fwd<<<dim3(g * 128), dim3(256), 0, stream>>>(x, ws, base);
        k_col<<<dim3(g * 64), dim3(512), 0, stream>>>(ws, filt, base);
        k_row_inv<<<dim3(g * 128), dim3(256), 0, stream>>>(ws, out, base);
    }
}